// Round 10
// baseline (257.383 us; speedup 1.0000x reference)
//
#include <hip/hip_runtime.h>
#include <hip/hip_fp16.h>
#include <math.h>

#define N_NODES 50000
#define N_EDGES 800000
#define NEG_SLOPE 0.2f
#define BN_EPS 1e-5f

#define CAP 96                   // bucket capacity; Poisson(16) => P(deg>96) ~ 0

// ---- workspace layout (bytes) ----
#define WS_FEAT    0u            // 50000*128 fp16 = 12,800,000
#define WS_EL      25600000u     // 50000*8 f32 = 1,600,000
#define WS_ER      27200000u     // 1,600,000
#define WS_CURSOR  28800000u     // 50176 ints = 200,704
#define WS_GPART   29000704u     // 16*256 f32 = 16,384
#define WS_CSR     29017088u     // 50000*96 ints = 19,200,000 (ends 48,217,088)
#define ZERO_START WS_CURSOR
#define ZERO_BYTES (WS_CSR - WS_CURSOR)   // cursor + gpart

#define GEMM_TILES 782           // ceil(50000/64)
#define SCAT_BLOCKS 782          // scatter blocks (first), 4 edges/thread
#define SCAT_THREADS (SCAT_BLOCKS * 256)  // 200192; *4 = 800768 >= N_EDGES
#define AGG_BLOCKS 2048          // 8 blocks/CU -> full 32 waves/CU
#define AGG_WAVES (AGG_BLOCKS * 4)
#define NPART 16                 // gpart copies

// ---------------------------------------------------------------------------
// k1: scatter blocks (0..781, 4-edge batched MLP) + GEMM tiles (782..1563).
// Scatter first so its latency hides under co-resident GEMM compute.
// GEMM: feat(fp16) = h @ W, 64-row tile (Hs stride 132 = conflict-free,
// learned the hard way in R9: stride 128 -> 16-way bank conflict, +37 us),
// W from L2, fused el/er epilogue (f32).
// ---------------------------------------------------------------------------
__global__ __launch_bounds__(256) void k1(
    const float* __restrict__ hin, const float* __restrict__ W,
    const float* __restrict__ attn_l, const float* __restrict__ attn_r,
    const int* __restrict__ src, const int* __restrict__ dst,
    int* __restrict__ cursor, int* __restrict__ csr,
    __half* __restrict__ feath, float* __restrict__ el, float* __restrict__ er)
{
    __shared__ float Hs[64 * 132];   // 33.8 KB, stride 132: bank-conflict-free

    if (blockIdx.x < SCAT_BLOCKS) {
        // ---- scatter: 4 edges per thread, batched loads then 4 MLP chains ----
        int tid = blockIdx.x * 256 + threadIdx.x;
        int sj[4], dj[4];
        #pragma unroll
        for (int j = 0; j < 4; j++) {
            int e = tid + j * SCAT_THREADS;
            bool v = (e < N_EDGES);
            sj[j] = v ? src[e] : -1;
            dj[j] = v ? dst[e] : 0;
        }
        #pragma unroll
        for (int j = 0; j < 4; j++) {
            if (sj[j] >= 0) {
                int slot = atomicAdd(&cursor[dj[j]], 1);
                if (slot < CAP) csr[dj[j] * CAP + slot] = sj[j];
            }
        }
        return;
    }

    // ---- GEMM part ----
    const int t = threadIdx.x;
    const int row0 = (blockIdx.x - SCAT_BLOCKS) * 64;

    const float4* h4 = (const float4*)hin;
    #pragma unroll
    for (int i = 0; i < 8; i++) {
        int idx = t + 256 * i;            // 0..2047
        int r = idx >> 5, c4 = idx & 31;
        int gr = row0 + r;
        float4 v = make_float4(0.f, 0.f, 0.f, 0.f);
        if (gr < N_NODES) v = h4[gr * 32 + c4];
        *(float4*)&Hs[r * 132 + c4 * 4] = v;
    }
    __syncthreads();

    const int tx = t & 15, ty = t >> 4;
    const int c0 = tx * 8, r0 = ty * 4;

    float acc[4][8];
    #pragma unroll
    for (int r = 0; r < 4; r++)
        #pragma unroll
        for (int j = 0; j < 8; j++) acc[r][j] = 0.f;

    const float4* W4 = (const float4*)W;          // [128][32] float4, L2-resident
    const float4* A0 = (const float4*)&Hs[(r0 + 0) * 132];
    const float4* A1 = (const float4*)&Hs[(r0 + 1) * 132];
    const float4* A2 = (const float4*)&Hs[(r0 + 2) * 132];
    const float4* A3 = (const float4*)&Hs[(r0 + 3) * 132];

    #pragma unroll 2
    for (int k4 = 0; k4 < 32; k4++) {
        float4 a0 = A0[k4], a1 = A1[k4], a2 = A2[k4], a3 = A3[k4];
        float Av0[4] = {a0.x, a0.y, a0.z, a0.w};
        float Av1[4] = {a1.x, a1.y, a1.z, a1.w};
        float Av2[4] = {a2.x, a2.y, a2.z, a2.w};
        float Av3[4] = {a3.x, a3.y, a3.z, a3.w};
        int kb = k4 * 4;
        #pragma unroll
        for (int kk = 0; kk < 4; kk++) {
            float4 b0 = W4[(kb + kk) * 32 + tx * 2];
            float4 b1 = W4[(kb + kk) * 32 + tx * 2 + 1];
            float av[4] = {Av0[kk], Av1[kk], Av2[kk], Av3[kk]};
            #pragma unroll
            for (int r = 0; r < 4; r++) {
                acc[r][0] += av[r] * b0.x; acc[r][1] += av[r] * b0.y;
                acc[r][2] += av[r] * b0.z; acc[r][3] += av[r] * b0.w;
                acc[r][4] += av[r] * b1.x; acc[r][5] += av[r] * b1.y;
                acc[r][6] += av[r] * b1.z; acc[r][7] += av[r] * b1.w;
            }
        }
    }

    const int h = tx >> 1;
    const int dbase = (tx & 1) * 8;
    float elv[4], erv[4];
    #pragma unroll
    for (int r = 0; r < 4; r++) {
        float e = 0.f, f = 0.f;
        #pragma unroll
        for (int j = 0; j < 8; j++) {
            float al = attn_l[h * 16 + dbase + j];
            float ar = attn_r[h * 16 + dbase + j];
            e += acc[r][j] * al; f += acc[r][j] * ar;
        }
        elv[r] = e + __shfl_xor(e, 1);
        erv[r] = f + __shfl_xor(f, 1);
    }

    #pragma unroll
    for (int r = 0; r < 4; r++) {
        int gr = row0 + r0 + r;
        if (gr < N_NODES) {
            __half2 p0 = __floats2half2_rn(acc[r][0], acc[r][1]);
            __half2 p1 = __floats2half2_rn(acc[r][2], acc[r][3]);
            __half2 p2 = __floats2half2_rn(acc[r][4], acc[r][5]);
            __half2 p3 = __floats2half2_rn(acc[r][6], acc[r][7]);
            uint4 u;
            u.x = *(unsigned int*)&p0;
            u.y = *(unsigned int*)&p1;
            u.z = *(unsigned int*)&p2;
            u.w = *(unsigned int*)&p3;
            *(uint4*)&feath[gr * 128 + c0] = u;
            if ((tx & 1) == 0) { el[gr * 8 + h] = elv[r]; er[gr * 8 + h] = erv[r]; }
        }
    }
}

// ---------------------------------------------------------------------------
// k_agg: fused softmax-aggregate, grid-stride 1 wave/node, fp16 feat gather.
// Lane l owns output dims {2l,2l+1}; head h = l>>3.
// BN partials in registers -> LDS reduce -> 256 atomics into gpart[b%16].
// ---------------------------------------------------------------------------
__global__ __launch_bounds__(256) void k_agg(
    const __half* __restrict__ feath, const float* __restrict__ el,
    const float* __restrict__ er, const int* __restrict__ cursor,
    const int* __restrict__ csr, float* __restrict__ outf,
    float* __restrict__ gpart)
{
    __shared__ float rs[512], rq[512];
    int t = threadIdx.x, lane = t & 63, w = t >> 6;
    int h = lane >> 3;
    const __half2* feat2 = (const __half2*)feath;

    float bs0 = 0.f, bq0 = 0.f, bs1 = 0.f, bq1 = 0.f;

    for (int n = (blockIdx.x * 256 + t) >> 6; n < N_NODES; n += AGG_WAVES) {
        int cnt = cursor[n]; if (cnt > CAP) cnt = CAP;
        const int* bucket = csr + n * CAP;
        float er_nh = er[n * 8 + h];
        float sum = 0.f, ax = 0.f, ay = 0.f;
        int p = 0;
        for (; p + 4 <= cnt; p += 4) {
            int s0 = bucket[p + 0], s1 = bucket[p + 1];
            int s2 = bucket[p + 2], s3 = bucket[p + 3];
            float e0 = el[s0 * 8 + h] + er_nh;
            float e1 = el[s1 * 8 + h] + er_nh;
            float e2 = el[s2 * 8 + h] + er_nh;
            float e3 = el[s3 * 8 + h] + er_nh;
            e0 = e0 > 0.f ? e0 : NEG_SLOPE * e0;
            e1 = e1 > 0.f ? e1 : NEG_SLOPE * e1;
            e2 = e2 > 0.f ? e2 : NEG_SLOPE * e2;
            e3 = e3 > 0.f ? e3 : NEG_SLOPE * e3;
            float a0 = __expf(e0), a1 = __expf(e1);
            float a2 = __expf(e2), a3 = __expf(e3);
            float2 f0 = __half22float2(feat2[s0 * 64 + lane]);
            float2 f1 = __half22float2(feat2[s1 * 64 + lane]);
            float2 f2 = __half22float2(feat2[s2 * 64 + lane]);
            float2 f3 = __half22float2(feat2[s3 * 64 + lane]);
            sum += (a0 + a1) + (a2 + a3);
            ax += a0 * f0.x; ay += a0 * f0.y;
            ax += a1 * f1.x; ay += a1 * f1.y;
            ax += a2 * f2.x; ay += a2 * f2.y;
            ax += a3 * f3.x; ay += a3 * f3.y;
        }
        for (; p < cnt; p++) {
            int s = bucket[p];
            float e = el[s * 8 + h] + er_nh;
            e = e > 0.f ? e : NEG_SLOPE * e;
            float a = __expf(e);
            float2 f = __half22float2(feat2[s * 64 + lane]);
            sum += a; ax += a * f.x; ay += a * f.y;
        }
        float rden = sum > 0.f ? 1.f / sum : 0.f;
        float ox = ax * rden, oy = ay * rden;
        ((float2*)outf)[n * 64 + lane] = make_float2(ox, oy);
        bs0 += ox; bq0 += ox * ox; bs1 += oy; bq1 += oy * oy;
    }

    rs[w * 128 + lane * 2]     = bs0;
    rs[w * 128 + lane * 2 + 1] = bs1;
    rq[w * 128 + lane * 2]     = bq0;
    rq[w * 128 + lane * 2 + 1] = bq1;
    __syncthreads();
    float* gp = gpart + (blockIdx.x & (NPART - 1)) * 256;
    if (t < 128) {
        float s = rs[t] + rs[128 + t] + rs[256 + t] + rs[384 + t];
        atomicAdd(&gp[t], s);
    } else {
        int c = t - 128;
        float q = rq[c] + rq[128 + c] + rq[256 + c] + rq[384 + c];
        atomicAdd(&gp[128 + c], q);
    }
}

// ---------------------------------------------------------------------------
// k_final: sum the NPART gpart copies, BN normalize + ELU + residual in place.
// ---------------------------------------------------------------------------
__global__ __launch_bounds__(256) void k_final(
    const float* __restrict__ hin, const float* __restrict__ gpart,
    const float* __restrict__ gamma, const float* __restrict__ beta,
    float* __restrict__ out)
{
    int i = blockIdx.x * blockDim.x + threadIdx.x;   // float4 index
    if (i >= N_NODES * 32) return;
    int c4 = i & 31;

    float4 sm = make_float4(0.f, 0.f, 0.f, 0.f);
    float4 sq = make_float4(0.f, 0.f, 0.f, 0.f);
    #pragma unroll
    for (int r = 0; r < NPART; r++) {
        float4 a = ((const float4*)(gpart + r * 256))[c4];
        float4 b = ((const float4*)(gpart + r * 256 + 128))[c4];
        sm.x += a.x; sm.y += a.y; sm.z += a.z; sm.w += a.w;
        sq.x += b.x; sq.y += b.y; sq.z += b.z; sq.w += b.w;
    }

    float4 x  = ((const float4*)out)[i];
    float4 hv = ((const float4*)hin)[i];
    float4 g  = ((const float4*)gamma)[c4];
    float4 bt = ((const float4*)beta)[c4];
    const float invN = 1.0f / (float)N_NODES;

    float mean, var, rstd, y;
    mean = sm.x * invN; var = sq.x * invN - mean * mean; rstd = rsqrtf(var + BN_EPS);
    y = g.x * (x.x - mean) * rstd + bt.x; y = y > 0.f ? y : (__expf(y) - 1.f); x.x = hv.x + y;
    mean = sm.y * invN; var = sq.y * invN - mean * mean; rstd = rsqrtf(var + BN_EPS);
    y = g.y * (x.y - mean) * rstd + bt.y; y = y > 0.f ? y : (__expf(y) - 1.f); x.y = hv.y + y;
    mean = sm.z * invN; var = sq.z * invN - mean * mean; rstd = rsqrtf(var + BN_EPS);
    y = g.z * (x.z - mean) * rstd + bt.z; y = y > 0.f ? y : (__expf(y) - 1.f); x.z = hv.z + y;
    mean = sm.w * invN; var = sq.w * invN - mean * mean; rstd = rsqrtf(var + BN_EPS);
    y = g.w * (x.w - mean) * rstd + bt.w; y = y > 0.f ? y : (__expf(y) - 1.f); x.w = hv.w + y;

    ((float4*)out)[i] = x;
}

// ===========================================================================
extern "C" void kernel_launch(void* const* d_in, const int* in_sizes, int n_in,
                              void* d_out, int out_size, void* d_ws, size_t ws_size,
                              hipStream_t stream)
{
    const float* hin    = (const float*)d_in[0];
    const int*   src    = (const int*)d_in[1];
    const int*   dst    = (const int*)d_in[2];
    const float* W      = (const float*)d_in[3];
    const float* attn_l = (const float*)d_in[4];
    const float* attn_r = (const float*)d_in[5];
    const float* gamma  = (const float*)d_in[6];
    const float* beta   = (const float*)d_in[7];
    float* out = (float*)d_out;

    char* ws = (char*)d_ws;
    __half* feath = (__half*)(ws + WS_FEAT);
    float* el     = (float*)(ws + WS_EL);
    float* er     = (float*)(ws + WS_ER);
    int*   cursor = (int*)(ws + WS_CURSOR);
    float* gpart  = (float*)(ws + WS_GPART);
    int*   csr    = (int*)(ws + WS_CSR);

    hipMemsetAsync(ws + ZERO_START, 0, ZERO_BYTES, stream);
    k1<<<SCAT_BLOCKS + GEMM_TILES, 256, 0, stream>>>(
        hin, W, attn_l, attn_r, src, dst, cursor, csr, feath, el, er);
    k_agg<<<AGG_BLOCKS, 256, 0, stream>>>(feath, el, er, cursor, csr, out, gpart);
    k_final<<<(N_NODES * 32) / 256, 256, 0, stream>>>(hin, gpart, gamma, beta, out);
}

// Round 13
// 204.322 us; speedup vs baseline: 1.2597x; 1.2597x over previous
//
#include <hip/hip_runtime.h>
#include <hip/hip_fp16.h>
#include <math.h>

#define N_NODES 50000
#define N_EDGES 800000
#define NEG_SLOPE 0.2f
#define BN_EPS 1e-5f

#define CAP 96                   // bucket capacity; Poisson(16) => P(deg>96) ~ 0

// ---- workspace layout (bytes) ----
#define WS_FEAT    0u            // 50000*128 fp16 = 12,800,000
#define WS_EL      25600000u     // 50000*8 f32 = 1,600,000
#define WS_ER      27200000u     // 1,600,000
#define WS_CURSOR  28800000u     // 50176 ints = 200,704
#define WS_GPART   29000704u     // 16*256 f32 = 16,384
#define WS_CSR     29017088u     // 50000*96 ints = 19,200,000 (ends 48,217,088)
#define ZERO_START WS_CURSOR
#define ZERO_BYTES (WS_CSR - WS_CURSOR)   // cursor + gpart

#define GEMM_TILES 782           // ceil(50000/64)
#define SCAT_BLOCKS 3125         // 800000/256, 1 edge/thread (R8-proven)
#define AGG_BLOCKS 2048          // 8 blocks/CU -> full 32 waves/CU
#define AGG_WAVES (AGG_BLOCKS * 4)
#define NPART 16                 // gpart copies

// ---------------------------------------------------------------------------
// k1: GEMM tiles (blocks 0..781) + bucket-CSR scatter (782..3906).
// R8-proven structure: GEMM first, scatter tail 1 edge/thread (max TLP).
// R9/R10 lessons: scatter-first + 4-edge batching = +40us; Hs stride 128 =
// 16-way bank conflict (+37us). Keep stride 132, keep this block order.
// GEMM: feat(fp16) = h @ W, 64-row tile, W from L2, fused el/er epilogue.
// ---------------------------------------------------------------------------
__global__ __launch_bounds__(256) void k1(
    const float* __restrict__ hin, const float* __restrict__ W,
    const float* __restrict__ attn_l, const float* __restrict__ attn_r,
    const int* __restrict__ src, const int* __restrict__ dst,
    int* __restrict__ cursor, int* __restrict__ csr,
    __half* __restrict__ feath, float* __restrict__ el, float* __restrict__ er)
{
    __shared__ float Hs[64 * 132];   // 33.8 KB, stride 132: bank-conflict-free

    if (blockIdx.x >= GEMM_TILES) {
        // ---- scatter: 1 edge/thread ----
        int i = (blockIdx.x - GEMM_TILES) * 256 + threadIdx.x;
        if (i < N_EDGES) {
            int s = src[i], d = dst[i];
            int slot = atomicAdd(&cursor[d], 1);
            if (slot < CAP) csr[d * CAP + slot] = s;
        }
        return;
    }

    // ---- GEMM part ----
    const int t = threadIdx.x;
    const int row0 = blockIdx.x * 64;

    const float4* h4 = (const float4*)hin;
    #pragma unroll
    for (int i = 0; i < 8; i++) {
        int idx = t + 256 * i;            // 0..2047
        int r = idx >> 5, c4 = idx & 31;
        int gr = row0 + r;
        float4 v = make_float4(0.f, 0.f, 0.f, 0.f);
        if (gr < N_NODES) v = h4[gr * 32 + c4];
        *(float4*)&Hs[r * 132 + c4 * 4] = v;
    }
    __syncthreads();

    const int tx = t & 15, ty = t >> 4;
    const int c0 = tx * 8, r0 = ty * 4;

    float acc[4][8];
    #pragma unroll
    for (int r = 0; r < 4; r++)
        #pragma unroll
        for (int j = 0; j < 8; j++) acc[r][j] = 0.f;

    const float4* W4 = (const float4*)W;          // [128][32] float4, L2-resident
    const float4* A0 = (const float4*)&Hs[(r0 + 0) * 132];
    const float4* A1 = (const float4*)&Hs[(r0 + 1) * 132];
    const float4* A2 = (const float4*)&Hs[(r0 + 2) * 132];
    const float4* A3 = (const float4*)&Hs[(r0 + 3) * 132];

    #pragma unroll 2
    for (int k4 = 0; k4 < 32; k4++) {
        float4 a0 = A0[k4], a1 = A1[k4], a2 = A2[k4], a3 = A3[k4];
        float Av0[4] = {a0.x, a0.y, a0.z, a0.w};
        float Av1[4] = {a1.x, a1.y, a1.z, a1.w};
        float Av2[4] = {a2.x, a2.y, a2.z, a2.w};
        float Av3[4] = {a3.x, a3.y, a3.z, a3.w};
        int kb = k4 * 4;
        #pragma unroll
        for (int kk = 0; kk < 4; kk++) {
            float4 b0 = W4[(kb + kk) * 32 + tx * 2];
            float4 b1 = W4[(kb + kk) * 32 + tx * 2 + 1];
            float av[4] = {Av0[kk], Av1[kk], Av2[kk], Av3[kk]};
            #pragma unroll
            for (int r = 0; r < 4; r++) {
                acc[r][0] += av[r] * b0.x; acc[r][1] += av[r] * b0.y;
                acc[r][2] += av[r] * b0.z; acc[r][3] += av[r] * b0.w;
                acc[r][4] += av[r] * b1.x; acc[r][5] += av[r] * b1.y;
                acc[r][6] += av[r] * b1.z; acc[r][7] += av[r] * b1.w;
            }
        }
    }

    const int h = tx >> 1;
    const int dbase = (tx & 1) * 8;
    float elv[4], erv[4];
    #pragma unroll
    for (int r = 0; r < 4; r++) {
        float e = 0.f, f = 0.f;
        #pragma unroll
        for (int j = 0; j < 8; j++) {
            float al = attn_l[h * 16 + dbase + j];
            float ar = attn_r[h * 16 + dbase + j];
            e += acc[r][j] * al; f += acc[r][j] * ar;
        }
        elv[r] = e + __shfl_xor(e, 1);
        erv[r] = f + __shfl_xor(f, 1);
    }

    #pragma unroll
    for (int r = 0; r < 4; r++) {
        int gr = row0 + r0 + r;
        if (gr < N_NODES) {
            __half2 p0 = __floats2half2_rn(acc[r][0], acc[r][1]);
            __half2 p1 = __floats2half2_rn(acc[r][2], acc[r][3]);
            __half2 p2 = __floats2half2_rn(acc[r][4], acc[r][5]);
            __half2 p3 = __floats2half2_rn(acc[r][6], acc[r][7]);
            uint4 u;
            u.x = *(unsigned int*)&p0;
            u.y = *(unsigned int*)&p1;
            u.z = *(unsigned int*)&p2;
            u.w = *(unsigned int*)&p3;
            *(uint4*)&feath[gr * 128 + c0] = u;
            if ((tx & 1) == 0) { el[gr * 8 + h] = elv[r]; er[gr * 8 + h] = erv[r]; }
        }
    }
}

// ---------------------------------------------------------------------------
// k_agg: fused softmax-aggregate, grid-stride 1 wave/node, fp16 feat gather.
// 8-wide unrolled edge loop with int4 bucket loads -> 8 independent gather
// chains in flight per wave (latency hiding). Lane l owns dims {2l,2l+1}.
// BN partials in registers -> LDS reduce -> 256 atomics into gpart[b%16].
// ---------------------------------------------------------------------------
__global__ __launch_bounds__(256) void k_agg(
    const __half* __restrict__ feath, const float* __restrict__ el,
    const float* __restrict__ er, const int* __restrict__ cursor,
    const int* __restrict__ csr, float* __restrict__ outf,
    float* __restrict__ gpart)
{
    __shared__ float rs[512], rq[512];
    int t = threadIdx.x, lane = t & 63, w = t >> 6;
    int h = lane >> 3;
    const __half2* feat2 = (const __half2*)feath;

    float bs0 = 0.f, bq0 = 0.f, bs1 = 0.f, bq1 = 0.f;

    for (int n = (blockIdx.x * 256 + t) >> 6; n < N_NODES; n += AGG_WAVES) {
        int cnt = cursor[n]; if (cnt > CAP) cnt = CAP;
        const int* bucket = csr + n * CAP;
        float er_nh = er[n * 8 + h];
        float sum = 0.f, ax = 0.f, ay = 0.f;
        int p = 0;
        for (; p + 8 <= cnt; p += 8) {
            int4 b0 = *(const int4*)&bucket[p];
            int4 b1 = *(const int4*)&bucket[p + 4];
            int si[8] = {b0.x, b0.y, b0.z, b0.w, b1.x, b1.y, b1.z, b1.w};
            float ev[8];
            #pragma unroll
            for (int j = 0; j < 8; j++) ev[j] = el[si[j] * 8 + h] + er_nh;
            float2 fv[8];
            #pragma unroll
            for (int j = 0; j < 8; j++) fv[j] = __half22float2(feat2[si[j] * 64 + lane]);
            #pragma unroll
            for (int j = 0; j < 8; j++) {
                float e = ev[j];
                e = e > 0.f ? e : NEG_SLOPE * e;
                float a = __expf(e);
                sum += a;
                ax += a * fv[j].x;
                ay += a * fv[j].y;
            }
        }
        for (; p + 4 <= cnt; p += 4) {
            int4 b0 = *(const int4*)&bucket[p];
            int si[4] = {b0.x, b0.y, b0.z, b0.w};
            float ev[4];
            #pragma unroll
            for (int j = 0; j < 4; j++) ev[j] = el[si[j] * 8 + h] + er_nh;
            float2 fv[4];
            #pragma unroll
            for (int j = 0; j < 4; j++) fv[j] = __half22float2(feat2[si[j] * 64 + lane]);
            #pragma unroll
            for (int j = 0; j < 4; j++) {
                float e = ev[j];
                e = e > 0.f ? e : NEG_SLOPE * e;
                float a = __expf(e);
                sum += a;
                ax += a * fv[j].x;
                ay += a * fv[j].y;
            }
        }
        for (; p < cnt; p++) {
            int s = bucket[p];
            float e = el[s * 8 + h] + er_nh;
            e = e > 0.f ? e : NEG_SLOPE * e;
            float a = __expf(e);
            float2 f = __half22float2(feat2[s * 64 + lane]);
            sum += a; ax += a * f.x; ay += a * f.y;
        }
        float rden = sum > 0.f ? 1.f / sum : 0.f;
        float ox = ax * rden, oy = ay * rden;
        ((float2*)outf)[n * 64 + lane] = make_float2(ox, oy);
        bs0 += ox; bq0 += ox * ox; bs1 += oy; bq1 += oy * oy;
    }

    rs[w * 128 + lane * 2]     = bs0;
    rs[w * 128 + lane * 2 + 1] = bs1;
    rq[w * 128 + lane * 2]     = bq0;
    rq[w * 128 + lane * 2 + 1] = bq1;
    __syncthreads();
    float* gp = gpart + (blockIdx.x & (NPART - 1)) * 256;
    if (t < 128) {
        float s = rs[t] + rs[128 + t] + rs[256 + t] + rs[384 + t];
        atomicAdd(&gp[t], s);
    } else {
        int c = t - 128;
        float q = rq[c] + rq[128 + c] + rq[256 + c] + rq[384 + c];
        atomicAdd(&gp[128 + c], q);
    }
}

// ---------------------------------------------------------------------------
// k_final: sum the NPART gpart copies, BN normalize + ELU + residual in place.
// ---------------------------------------------------------------------------
__global__ __launch_bounds__(256) void k_final(
    const float* __restrict__ hin, const float* __restrict__ gpart,
    const float* __restrict__ gamma, const float* __restrict__ beta,
    float* __restrict__ out)
{
    int i = blockIdx.x * blockDim.x + threadIdx.x;   // float4 index
    if (i >= N_NODES * 32) return;
    int c4 = i & 31;

    float4 sm = make_float4(0.f, 0.f, 0.f, 0.f);
    float4 sq = make_float4(0.f, 0.f, 0.f, 0.f);
    #pragma unroll
    for (int r = 0; r < NPART; r++) {
        float4 a = ((const float4*)(gpart + r * 256))[c4];
        float4 b = ((const float4*)(gpart + r * 256 + 128))[c4];
        sm.x += a.x; sm.y += a.y; sm.z += a.z; sm.w += a.w;
        sq.x += b.x; sq.y += b.y; sq.z += b.z; sq.w += b.w;
    }

    float4 x  = ((const float4*)out)[i];
    float4 hv = ((const float4*)hin)[i];
    float4 g  = ((const float4*)gamma)[c4];
    float4 bt = ((const float4*)beta)[c4];
    const float invN = 1.0f / (float)N_NODES;

    float mean, var, rstd, y;
    mean = sm.x * invN; var = sq.x * invN - mean * mean; rstd = rsqrtf(var + BN_EPS);
    y = g.x * (x.x - mean) * rstd + bt.x; y = y > 0.f ? y : (__expf(y) - 1.f); x.x = hv.x + y;
    mean = sm.y * invN; var = sq.y * invN - mean * mean; rstd = rsqrtf(var + BN_EPS);
    y = g.y * (x.y - mean) * rstd + bt.y; y = y > 0.f ? y : (__expf(y) - 1.f); x.y = hv.y + y;
    mean = sm.z * invN; var = sq.z * invN - mean * mean; rstd = rsqrtf(var + BN_EPS);
    y = g.z * (x.z - mean) * rstd + bt.z; y = y > 0.f ? y : (__expf(y) - 1.f); x.z = hv.z + y;
    mean = sm.w * invN; var = sq.w * invN - mean * mean; rstd = rsqrtf(var + BN_EPS);
    y = g.w * (x.w - mean) * rstd + bt.w; y = y > 0.f ? y : (__expf(y) - 1.f); x.w = hv.w + y;

    ((float4*)out)[i] = x;
}

// ===========================================================================
extern "C" void kernel_launch(void* const* d_in, const int* in_sizes, int n_in,
                              void* d_out, int out_size, void* d_ws, size_t ws_size,
                              hipStream_t stream)
{
    const float* hin    = (const float*)d_in[0];
    const int*   src    = (const int*)d_in[1];
    const int*   dst    = (const int*)d_in[2];
    const float* W      = (const float*)d_in[3];
    const float* attn_l = (const float*)d_in[4];
    const float* attn_r = (const float*)d_in[5];
    const float* gamma  = (const float*)d_in[6];
    const float* beta   = (const float*)d_in[7];
    float* out = (float*)d_out;

    char* ws = (char*)d_ws;
    __half* feath = (__half*)(ws + WS_FEAT);
    float* el     = (float*)(ws + WS_EL);
    float* er     = (float*)(ws + WS_ER);
    int*   cursor = (int*)(ws + WS_CURSOR);
    float* gpart  = (float*)(ws + WS_GPART);
    int*   csr    = (int*)(ws + WS_CSR);

    hipMemsetAsync(ws + ZERO_START, 0, ZERO_BYTES, stream);
    k1<<<GEMM_TILES + SCAT_BLOCKS, 256, 0, stream>>>(
        hin, W, attn_l, attn_r, src, dst, cursor, csr, feath, el, er);
    k_agg<<<AGG_BLOCKS, 256, 0, stream>>>(feath, el, er, cursor, csr, out, gpart);
    k_final<<<(N_NODES * 32) / 256, 256, 0, stream>>>(hin, gpart, gamma, beta, out);
}